// Round 1
// baseline (739.685 us; speedup 1.0000x reference)
//
#include <hip/hip_runtime.h>

#define DD 768
#define P 196
#define PP 224          // P padded to 7*32 for 32x32 MFMA tiles
#define NIMG 64
#define N_NORMAL 32
#define MARGIN 0.5f

typedef __bf16 bf16;
typedef __bf16 bf16x8 __attribute__((ext_vector_type(8)));   // 4 VGPRs, MFMA A/B frag
typedef float floatx16 __attribute__((ext_vector_type(16))); // MFMA C/D frag

// ---------------------------------------------------------------------------
// Kernel 1: L2-normalize each patch vector (fp32) and cast to bf16 into a
// padded [64][224][768] layout. Pad rows (p>=196) are zeroed.
// ---------------------------------------------------------------------------
__global__ __launch_bounds__(256) void norm_kernel(const float* __restrict__ nrm,
                                                   const float* __restrict__ dft,
                                                   bf16* __restrict__ Y) {
    int row = blockIdx.x;            // 0 .. 64*224-1
    int img = row / PP;
    int p   = row % PP;
    int tid = threadIdx.x;           // 256 threads, 3 elems each (768 = 3*256)
    bf16* yr = Y + (size_t)row * DD;
    if (p >= P) {
        bf16 z = (bf16)0.0f;
        yr[tid] = z; yr[tid + 256] = z; yr[tid + 512] = z;
        return;
    }
    const float* src = (img < N_NORMAL)
        ? nrm + ((size_t)img * P + p) * DD
        : dft + ((size_t)(img - N_NORMAL) * P + p) * DD;
    float x0 = src[tid], x1 = src[tid + 256], x2 = src[tid + 512];
    float ss = x0 * x0 + x1 * x1 + x2 * x2;
    #pragma unroll
    for (int o = 32; o > 0; o >>= 1) ss += __shfl_down(ss, o);
    __shared__ float red[4];
    int lane = tid & 63, wv = tid >> 6;
    if (lane == 0) red[wv] = ss;
    __syncthreads();
    float tot = red[0] + red[1] + red[2] + red[3];
    float inv = 1.0f / (sqrtf(tot) + 1e-8f);
    yr[tid]       = (bf16)(x0 * inv);
    yr[tid + 256] = (bf16)(x1 * inv);
    yr[tid + 512] = (bf16)(x2 * inv);
}

// ---------------------------------------------------------------------------
// Kernel 2: one block per (i,j) pair. 448 threads = 7 waves; wave w owns
// p-tile w (rows w*32..w*32+31 of image i) x all 7 q-tiles of image j.
// S[p][q] = <n_i[p], n_j[q]> via v_mfma_f32_32x32x16_bf16 (K-loop over 768).
// Then column-max over valid p, and accumulate the loss term via atomicAdd.
// Fragment layouts (gfx950, HW-verified per guide):
//   A/B: elem [m = lane&31][k = (lane>>5)*8 + j], j in 0..7
//   C/D: col = lane&31, row = (reg&3) + 8*(reg>>2) + 4*(lane>>5)
// ---------------------------------------------------------------------------
__global__ __launch_bounds__(448) void pair_kernel(const bf16* __restrict__ Y,
                                                   float* __restrict__ out) {
    int b = blockIdx.x;
    bool is_nn = (b < 1024);
    int pi = (b & 1023) >> 5;
    int pj = (b & 1023) & 31;
    if (is_nn && pi >= pj) return;     // only upper-triangular nn pairs
    int ja = is_nn ? pj : (N_NORMAL + pj);

    const bf16* Ab = Y + (size_t)pi * PP * DD;
    const bf16* Bb = Y + (size_t)ja * PP * DD;

    int tid   = threadIdx.x;
    int lane  = tid & 63;
    int w     = tid >> 6;              // 0..6 : p-tile index
    int lrow  = lane & 31;
    int khalf = lane >> 5;             // 0 or 1

    const bf16* aptr = Ab + (size_t)(w * 32 + lrow) * DD + khalf * 8;

    floatx16 acc[7];
    #pragma unroll
    for (int t = 0; t < 7; ++t)
        #pragma unroll
        for (int r = 0; r < 16; ++r) acc[t][r] = 0.0f;

    for (int k0 = 0; k0 < DD; k0 += 16) {
        bf16x8 af = *(const bf16x8*)(aptr + k0);
        #pragma unroll
        for (int t = 0; t < 7; ++t) {
            const bf16* bp = Bb + (size_t)(t * 32 + lrow) * DD + khalf * 8 + k0;
            bf16x8 bfr = *(const bf16x8*)bp;
            acc[t] = __builtin_amdgcn_mfma_f32_32x32x16_bf16(af, bfr, acc[t], 0, 0, 0);
        }
    }

    __shared__ float colmax_w[7][PP];
    #pragma unroll
    for (int t = 0; t < 7; ++t) {
        float m = -3.0e38f;
        #pragma unroll
        for (int r = 0; r < 16; ++r) {
            int plocal = (r & 3) + 8 * (r >> 2) + 4 * khalf;
            int pg = w * 32 + plocal;
            if (pg < P) m = fmaxf(m, acc[t][r]);   // mask pad rows out of max
        }
        m = fmaxf(m, __shfl_xor(m, 32));           // combine the two row-halves
        if (lane < 32) colmax_w[w][t * 32 + lrow] = m;
    }
    __syncthreads();

    // combine over the 7 p-tiles and form the loss contribution per q
    float c = 0.0f;
    if (tid < P) {
        float cm = colmax_w[0][tid];
        #pragma unroll
        for (int w2 = 1; w2 < 7; ++w2) cm = fmaxf(cm, colmax_w[w2][tid]);
        c = is_nn ? (1.0f - cm) * (1.0f / (496.0f * 196.0f))
                  : fmaxf(cm - MARGIN, 0.0f) * (1.0f / (32.0f * 32.0f * 196.0f));
    }
    #pragma unroll
    for (int o = 32; o > 0; o >>= 1) c += __shfl_down(c, o);
    __shared__ float redp[7];
    if (lane == 0) redp[w] = c;
    __syncthreads();
    if (tid == 0) {
        float s = 0.0f;
        #pragma unroll
        for (int w2 = 0; w2 < 7; ++w2) s += redp[w2];
        atomicAdd(out, s);
    }
}

// ---------------------------------------------------------------------------
extern "C" void kernel_launch(void* const* d_in, const int* in_sizes, int n_in,
                              void* d_out, int out_size, void* d_ws, size_t ws_size,
                              hipStream_t stream) {
    const float* nrm = (const float*)d_in[0];   // [32,196,768] fp32
    const float* dft = (const float*)d_in[1];   // [32,196,768] fp32
    float* out = (float*)d_out;                 // scalar fp32
    bf16* Y = (bf16*)d_ws;                      // [64,224,768] bf16 = 21 MB

    hipMemsetAsync(d_out, 0, sizeof(float), stream);
    norm_kernel<<<NIMG * PP, 256, 0, stream>>>(nrm, dft, Y);
    // 1024 nn slots (528 early-exit) + 1024 nd pairs
    pair_kernel<<<2048, 448, 0, stream>>>(Y, out);
}

// Round 2
// 364.906 us; speedup vs baseline: 2.0271x; 2.0271x over previous
//
#include <hip/hip_runtime.h>

#define DD 768
#define P 196
#define PP 224          // rows per image in workspace (7*32), rows 196..223 zeroed
#define NIMG 64
#define NN 32
#define MARGIN 0.5f
#define BK 64           // K-chunk staged per barrier
#define NCHUNK 12       // 768/64

typedef __bf16 bf16;
typedef __bf16 bf16x4 __attribute__((ext_vector_type(4)));
typedef __bf16 bf16x8 __attribute__((ext_vector_type(8)));   // 16 B, MFMA A/B frag
typedef float floatx4 __attribute__((ext_vector_type(4)));   // MFMA C/D frag (16x16)

// ---------------------------------------------------------------------------
// Kernel 1: wave-per-row L2-normalize (fp32) -> bf16 into padded [64][224][768].
// Also zero-initializes the scalar output (pair_kernel runs after, same stream).
// ---------------------------------------------------------------------------
__global__ __launch_bounds__(256) void norm_kernel(const float* __restrict__ nrm,
                                                   const float* __restrict__ dft,
                                                   bf16* __restrict__ Y,
                                                   float* __restrict__ out) {
    if (blockIdx.x == 0 && threadIdx.x == 0) out[0] = 0.0f;
    int row  = blockIdx.x * 4 + (threadIdx.x >> 6);   // 4 waves/block, 1 row/wave
    int lane = threadIdx.x & 63;
    int img = row / PP, p = row % PP;
    bf16* yr = Y + (size_t)row * DD;
    if (p >= P) {                                     // pad row -> zeros
        bf16x4 z = {(bf16)0.f, (bf16)0.f, (bf16)0.f, (bf16)0.f};
        #pragma unroll
        for (int j = 0; j < 3; ++j) *(bf16x4*)(yr + lane * 4 + j * 256) = z;
        return;
    }
    const float* src = (img < NN) ? nrm + ((size_t)img * P + p) * DD
                                  : dft + ((size_t)(img - NN) * P + p) * DD;
    float4 v[3];
    float ss = 0.f;
    #pragma unroll
    for (int j = 0; j < 3; ++j) {
        v[j] = *(const float4*)(src + lane * 4 + j * 256);
        ss += v[j].x * v[j].x + v[j].y * v[j].y + v[j].z * v[j].z + v[j].w * v[j].w;
    }
    #pragma unroll
    for (int o = 32; o > 0; o >>= 1) ss += __shfl_xor(ss, o);
    float inv = 1.0f / (sqrtf(ss) + 1e-8f);
    #pragma unroll
    for (int j = 0; j < 3; ++j) {
        bf16x4 w;
        w.x = (bf16)(v[j].x * inv);
        w.y = (bf16)(v[j].y * inv);
        w.z = (bf16)(v[j].z * inv);
        w.w = (bf16)(v[j].w * inv);
        *(bf16x4*)(yr + lane * 4 + j * 256) = w;
    }
}

// ---------------------------------------------------------------------------
// Kernel 2: one block per pair (496 nn + 1024 nd = 1520 blocks), 512 threads
// = 8 waves in a 4x2 grid. Wave (wr,wc): p-rows [wr*64, wr*64+63] (p padded
// to 256; rows >=224 clamp to the zero row 223), q-cols [wc*112, wc*112+111].
// Wave tile = 4x7 MFMA 16x16x32 sub-tiles -> 28 MFMA per K-step(32), B-frags
// from double-buffered LDS (K-major conflict-free layout), A-frags from L1.
// ---------------------------------------------------------------------------
__global__ __launch_bounds__(512, 2) void pair_kernel(const bf16* __restrict__ Y,
                                                      float* __restrict__ out) {
    __shared__ uint4 Bs[2][8 * PP];       // [buf][kg8*224 + row], 2 x 28 KB
    __shared__ float colmax[4][PP];
    __shared__ float redp[8];

    int b = blockIdx.x;
    int ia, ja; bool is_nn;
    if (b < 496) {
        is_nn = true;
        int i = 0, rem = b;
        while (rem >= 31 - i) { rem -= 31 - i; ++i; }   // triangular decode, i<j
        ia = i; ja = i + 1 + rem;
    } else {
        is_nn = false;
        int t = b - 496;
        ia = t >> 5; ja = NN + (t & 31);
    }
    const bf16* Ab = Y + (size_t)ia * PP * DD;
    const bf16* Bb = Y + (size_t)ja * PP * DD;

    int tid  = threadIdx.x;
    int lane = tid & 63;
    int wave = tid >> 6;            // 0..7
    int wr   = wave >> 1;           // 0..3 : 64 p-rows each
    int wc   = wave & 1;            // 0..1 : 112 q-cols each
    int r16  = lane & 15;
    int quad = lane >> 4;           // 0..3 (k-group of 8 for A/B frags)

    // A row pointers, fixed over K (clamped rows land on zero row 223)
    const bf16* arow[4];
    #pragma unroll
    for (int ps = 0; ps < 4; ++ps) {
        int r = wr * 64 + ps * 16 + r16;
        if (r > PP - 1) r = PP - 1;
        arow[ps] = Ab + (size_t)r * DD + quad * 8;
    }

    floatx4 acc[4][7];
    #pragma unroll
    for (int ps = 0; ps < 4; ++ps)
        #pragma unroll
        for (int t = 0; t < 7; ++t)
            acc[ps][t] = (floatx4){0.f, 0.f, 0.f, 0.f};

    // B staging: 224 rows x 64 k = 1792 pieces of 16 B; piece pc: row=pc>>3,
    // kg8=pc&7 (8 consecutive lanes read a full 128-B line of one row).
    uint4 tmp[4];

    auto gload = [&](int c) {
        #pragma unroll
        for (int u = 0; u < 3; ++u) {
            int pc = tid + u * 512;
            tmp[u] = *(const uint4*)(Bb + (size_t)(pc >> 3) * DD + c * BK + (pc & 7) * 8);
        }
        if (tid < 256) {
            int pc = tid + 1536;
            tmp[3] = *(const uint4*)(Bb + (size_t)(pc >> 3) * DD + c * BK + (pc & 7) * 8);
        }
    };
    auto lwrite = [&](int buf) {
        #pragma unroll
        for (int u = 0; u < 3; ++u) {
            int pc = tid + u * 512;
            Bs[buf][(pc & 7) * PP + (pc >> 3)] = tmp[u];
        }
        if (tid < 256) {
            int pc = tid + 1536;
            Bs[buf][(pc & 7) * PP + (pc >> 3)] = tmp[3];
        }
    };

    gload(0);
    lwrite(0);
    __syncthreads();

    for (int c = 0; c < NCHUNK; ++c) {
        if (c + 1 < NCHUNK) gload(c + 1);          // prefetch next chunk to regs

        // A-frags for both K-steps issued up-front (stay in flight over s=0 MFMAs)
        bf16x8 afrag[2][4];
        #pragma unroll
        for (int s = 0; s < 2; ++s)
            #pragma unroll
            for (int ps = 0; ps < 4; ++ps)
                afrag[s][ps] = *(const bf16x8*)(arow[ps] + c * BK + s * 32);

        int buf = c & 1;
        #pragma unroll
        for (int s = 0; s < 2; ++s) {
            const uint4* bsrc = &Bs[buf][(s * 4 + quad) * PP + wc * 112 + r16];
            bf16x8 bfrag[7];
            #pragma unroll
            for (int t = 0; t < 7; ++t)
                bfrag[t] = *(const bf16x8*)(bsrc + t * 16);
            #pragma unroll
            for (int ps = 0; ps < 4; ++ps)
                #pragma unroll
                for (int t = 0; t < 7; ++t)
                    acc[ps][t] = __builtin_amdgcn_mfma_f32_16x16x32_bf16(
                        afrag[s][ps], bfrag[t], acc[ps][t], 0, 0, 0);
        }

        if (c + 1 < NCHUNK) {
            lwrite((c + 1) & 1);                   // other buffer: safe, last read at c-1
            __syncthreads();
        }
    }

    // column-max over valid p (p<196; pad rows excluded), per q
    // C/D layout: col q = lane&15, row p = quad*4 + reg
    #pragma unroll
    for (int t = 0; t < 7; ++t) {
        float m = -3.0e38f;
        #pragma unroll
        for (int ps = 0; ps < 4; ++ps) {
            int pbase = wr * 64 + ps * 16 + quad * 4;
            #pragma unroll
            for (int r = 0; r < 4; ++r)
                if (pbase + r < P) m = fmaxf(m, acc[ps][t][r]);
        }
        m = fmaxf(m, __shfl_xor(m, 16));
        m = fmaxf(m, __shfl_xor(m, 32));
        if (quad == 0) colmax[wr][wc * 112 + t * 16 + r16] = m;
    }
    __syncthreads();

    float contrib = 0.f;
    if (tid < P) {
        float cm = fmaxf(fmaxf(colmax[0][tid], colmax[1][tid]),
                         fmaxf(colmax[2][tid], colmax[3][tid]));
        contrib = is_nn ? (1.0f - cm) * (1.0f / (496.0f * 196.0f))
                        : fmaxf(cm - MARGIN, 0.0f) * (1.0f / (1024.0f * 196.0f));
    }
    #pragma unroll
    for (int o = 32; o > 0; o >>= 1) contrib += __shfl_down(contrib, o);
    if (lane == 0) redp[wave] = contrib;
    __syncthreads();
    if (tid == 0) {
        float s = 0.f;
        #pragma unroll
        for (int w2 = 0; w2 < 8; ++w2) s += redp[w2];
        atomicAdd(out, s);
    }
}

// ---------------------------------------------------------------------------
extern "C" void kernel_launch(void* const* d_in, const int* in_sizes, int n_in,
                              void* d_out, int out_size, void* d_ws, size_t ws_size,
                              hipStream_t stream) {
    const float* nrm = (const float*)d_in[0];   // [32,196,768] fp32
    const float* dft = (const float*)d_in[1];   // [32,196,768] fp32
    float* out = (float*)d_out;                 // scalar fp32
    bf16* Y = (bf16*)d_ws;                      // [64,224,768] bf16 = 21 MB

    norm_kernel<<<NIMG * PP / 4, 256, 0, stream>>>(nrm, dft, Y, out);
    pair_kernel<<<496 + 1024, 512, 0, stream>>>(Y, out);
}